// Round 1
// baseline (176.039 us; speedup 1.0000x reference)
//
#include <hip/hip_runtime.h>

static constexpr int N_NODES = 8192;   // B*L
static constexpr int FEAT    = 128;
static constexpr int CS1     = 10;
static constexpr int CS2     = 10;

// ---------------- Kernel 1: gather + aggregate ----------------
// F layout: [n][j][d], j=0: feats1 (1-hop mean), j=1: feats2 (2-hop mean), j=2: self
__global__ void __launch_bounds__(128) gather_agg(
    const float* __restrict__ feat,
    const int*   __restrict__ nodes,
    const int*   __restrict__ n1,
    const int*   __restrict__ n2,
    float*       __restrict__ F)
{
    const int n = blockIdx.x;
    const int d = threadIdx.x;
    const int nf = nodes[n];

    const float sv = feat[(size_t)nf * FEAT + d];

    float a1 = 0.f;
#pragma unroll
    for (int s = 0; s < CS1; ++s) {
        const int i1 = n1[nf * CS1 + s];
        a1 += feat[(size_t)i1 * FEAT + d];
    }

    float a2 = 0.f;
    for (int t = 0; t < CS2; ++t) {
        const int m = n2[nf * CS2 + t];
#pragma unroll
        for (int s = 0; s < CS1; ++s) {
            const int i2 = n1[m * CS1 + s];
            a2 += feat[(size_t)i2 * FEAT + d];
        }
    }

    float* Fn = F + (size_t)n * (3 * FEAT);
    Fn[d]            = a1 * 0.1f;
    Fn[FEAT + d]     = a2 * 0.01f;
    Fn[2 * FEAT + d] = sv;
}

// ---------------- Kernel 2: GEMM + ReLU ----------------
// out[x][y] = relu(sum_d X[x][d] * W[y][d])
//   X = F viewed [24576][128]  (x = n*3 + j)
//   W = local_weight viewed [1024][128]  (y = c*128 + k)
// out flat index: n*3072 + c*384 + j*128 + k
static constexpr int TM = 64, TN = 64, KD = 128, PAD = 4;

__global__ void __launch_bounds__(256) proj_relu(
    const float* __restrict__ F,
    const float* __restrict__ W,
    float*       __restrict__ out)
{
    __shared__ float Xs[TM][KD + PAD];
    __shared__ float Ws[TN][KD + PAD];

    const int tid   = threadIdx.x;
    const int xBase = blockIdx.x * TM;
    const int yBase = blockIdx.y * TN;

    // stage: 64 rows x 128 floats = 2048 float4 per operand, 8 per thread
    {
        const float4* Xg = (const float4*)(F + (size_t)xBase * KD);
        const float4* Wg = (const float4*)(W + (size_t)yBase * KD);
#pragma unroll
        for (int p = 0; p < 8; ++p) {
            const int q   = tid + p * 256;
            const int row = q >> 5;   // q / 32
            const int c4  = q & 31;   // float4 index within row
            float4 v = Xg[(size_t)row * 32 + c4];
            *(float4*)&Xs[row][c4 * 4] = v;
            float4 w = Wg[(size_t)row * 32 + c4];
            *(float4*)&Ws[row][c4 * 4] = w;
        }
    }
    __syncthreads();

    const int ty = tid >> 4;   // 0..15
    const int tx = tid & 15;   // 0..15

    float acc[4][4];
#pragma unroll
    for (int i = 0; i < 4; ++i)
#pragma unroll
        for (int j = 0; j < 4; ++j) acc[i][j] = 0.f;

    // K loop, float4 LDS reads (ds_read_b128) -> FMA-bound
    for (int kk = 0; kk < KD; kk += 4) {
        float4 xv[4], wv[4];
#pragma unroll
        for (int i = 0; i < 4; ++i) xv[i] = *(const float4*)&Xs[ty + i * 16][kk];
#pragma unroll
        for (int j = 0; j < 4; ++j) wv[j] = *(const float4*)&Ws[tx + j * 16][kk];
#pragma unroll
        for (int i = 0; i < 4; ++i) {
#pragma unroll
            for (int j = 0; j < 4; ++j) {
                acc[i][j] = fmaf(xv[i].x, wv[j].x, acc[i][j]);
                acc[i][j] = fmaf(xv[i].y, wv[j].y, acc[i][j]);
                acc[i][j] = fmaf(xv[i].z, wv[j].z, acc[i][j]);
                acc[i][j] = fmaf(xv[i].w, wv[j].w, acc[i][j]);
            }
        }
    }

    // epilogue: scatter to output layout with ReLU
#pragma unroll
    for (int i = 0; i < 4; ++i) {
        const int x = xBase + ty + i * 16;
        const int n = x / 3;
        const int j = x - n * 3;
#pragma unroll
        for (int jj = 0; jj < 4; ++jj) {
            const int y = yBase + tx + jj * 16;
            const int c = y >> 7;
            const int k = y & 127;
            out[(size_t)n * 3072 + c * 384 + j * 128 + k] = fmaxf(acc[i][jj], 0.f);
        }
    }
}

extern "C" void kernel_launch(void* const* d_in, const int* in_sizes, int n_in,
                              void* d_out, int out_size, void* d_ws, size_t ws_size,
                              hipStream_t stream) {
    const float* features = (const float*)d_in[0];   // [100000,128] f32
    const float* lw       = (const float*)d_in[1];   // [8,128,128]  f32
    const int*   nodes    = (const int*)d_in[2];     // [1024,8]     i32
    const int*   n1       = (const int*)d_in[3];     // [100000,10]  i32
    const int*   n2       = (const int*)d_in[4];     // [100000,10]  i32
    float*       out      = (float*)d_out;           // [1024,8,8,384] f32
    float*       F        = (float*)d_ws;            // [24576,128] f32 = 12.6 MB

    gather_agg<<<N_NODES, 128, 0, stream>>>(features, nodes, n1, n2, F);

    dim3 grid(24576 / TM, 1024 / TN);  // 384 x 16
    proj_relu<<<grid, 256, 0, stream>>>(F, lw, out);
}

// Round 3
// 103.274 us; speedup vs baseline: 1.7046x; 1.7046x over previous
//
#include <hip/hip_runtime.h>

typedef __attribute__((ext_vector_type(8))) short bf16x8;
typedef __attribute__((ext_vector_type(4))) float f32x4;

static constexpr int N_NODES = 8192;   // B*L
static constexpr int FEAT    = 128;
static constexpr int CS1     = 10;
static constexpr int CS2     = 10;

__device__ __forceinline__ unsigned short f2bf(float f) {
    unsigned u = __builtin_bit_cast(unsigned, f);
    u += 0x7FFFu + ((u >> 16) & 1u);   // round-to-nearest-even
    return (unsigned short)(u >> 16);
}

// ---------------- Kernel 0: pack W fp32 -> bf16 ----------------
// lw flat [1024][128] row-major (y = c*128+k), 131072 floats
__global__ void __launch_bounds__(256) pack_w(const float* __restrict__ lw,
                                              unsigned short* __restrict__ Wp)
{
    const int i = blockIdx.x * 256 + threadIdx.x;   // 0..32767, 4 floats each
    const float4 v = ((const float4*)lw)[i];
    ushort4 o;
    o.x = f2bf(v.x); o.y = f2bf(v.y); o.z = f2bf(v.z); o.w = f2bf(v.w);
    ((ushort4*)Wp)[i] = o;
}

// ---------------- Kernel 1: gather + aggregate -> bf16 ----------------
// Three j-major matrices: F0=feats1, F1=feats2, F2=self, each [8192][128] bf16
__global__ void __launch_bounds__(128) gather_agg(
    const float* __restrict__ feat,
    const int*   __restrict__ nodes,
    const int*   __restrict__ n1,
    const int*   __restrict__ n2,
    unsigned short* __restrict__ F0,
    unsigned short* __restrict__ F1,
    unsigned short* __restrict__ F2)
{
    const int n = blockIdx.x;
    const int d = threadIdx.x;
    const int nf = nodes[n];

    const float sv = feat[(size_t)nf * FEAT + d];

    float a1 = 0.f;
#pragma unroll
    for (int s = 0; s < CS1; ++s) {
        const int i1 = n1[nf * CS1 + s];
        a1 += feat[(size_t)i1 * FEAT + d];
    }

    float a2 = 0.f;
    for (int t = 0; t < CS2; ++t) {
        const int m = n2[nf * CS2 + t];
#pragma unroll
        for (int s = 0; s < CS1; ++s) {
            const int i2 = n1[m * CS1 + s];
            a2 += feat[(size_t)i2 * FEAT + d];
        }
    }

    const size_t o = (size_t)n * FEAT + d;
    F0[o] = f2bf(a1 * 0.1f);
    F1[o] = f2bf(a2 * 0.01f);
    F2[o] = f2bf(sv);
}

// ---------------- Kernel 2: bf16 MFMA GEMM + ReLU ----------------
// C[x][y] = relu(sum_d X[x][d] * W[y][d]),  X=[24576][128] bf16 (x = j*8192+n),
// W=[1024][128] bf16 (y = c*128+k).
// out flat: n*3072 + c*384 + j*128 + k
// Per wave: 64(M) x 64(N) tile, K=128 fully in registers, no LDS.
__global__ void __launch_bounds__(256) proj_mfma(
    const unsigned short* __restrict__ F,
    const unsigned short* __restrict__ Wp,
    float* __restrict__ out)
{
    const int wave = threadIdx.x >> 6;
    const int lane = threadIdx.x & 63;
    const int xBase = blockIdx.x * 256 + wave * 64;
    const int yBase = blockIdx.y * 64;
    const int r = lane & 15;   // A row / B col within 16-tile
    const int q = lane >> 4;   // k-slot (8 contiguous K elems each)

    f32x4 acc[4][4];
#pragma unroll
    for (int mi = 0; mi < 4; ++mi)
#pragma unroll
        for (int nj = 0; nj < 4; ++nj) acc[mi][nj] = (f32x4){0.f, 0.f, 0.f, 0.f};

    const unsigned short* Arow = F  + (size_t)(xBase + r) * FEAT + q * 8;
    const unsigned short* Brow = Wp + (size_t)(yBase + r) * FEAT + q * 8;

#pragma unroll
    for (int k0 = 0; k0 < 4; ++k0) {           // K step = 32
        bf16x8 a[4], b[4];
#pragma unroll
        for (int mi = 0; mi < 4; ++mi)
            a[mi] = *(const bf16x8*)(Arow + (size_t)mi * 16 * FEAT + k0 * 32);
#pragma unroll
        for (int nj = 0; nj < 4; ++nj)
            b[nj] = *(const bf16x8*)(Brow + (size_t)nj * 16 * FEAT + k0 * 32);
#pragma unroll
        for (int mi = 0; mi < 4; ++mi)
#pragma unroll
            for (int nj = 0; nj < 4; ++nj)
                acc[mi][nj] = __builtin_amdgcn_mfma_f32_16x16x32_bf16(
                    a[mi], b[nj], acc[mi][nj], 0, 0, 0);
    }

    // epilogue: C/D layout col=lane&15, row=(lane>>4)*4+reg (m89-verified)
#pragma unroll
    for (int mi = 0; mi < 4; ++mi) {
#pragma unroll
        for (int i = 0; i < 4; ++i) {
            const int x = xBase + mi * 16 + q * 4 + i;
            const int n = x & 8191;
            const int j = x >> 13;
            float* orow = out + (size_t)n * 3072 + j * 128;
#pragma unroll
            for (int nj = 0; nj < 4; ++nj) {
                const int y = yBase + nj * 16 + r;
                const int c = y >> 7;
                const int k = y & 127;
                orow[c * 384 + k] = fmaxf(acc[mi][nj][i], 0.f);
            }
        }
    }
}

extern "C" void kernel_launch(void* const* d_in, const int* in_sizes, int n_in,
                              void* d_out, int out_size, void* d_ws, size_t ws_size,
                              hipStream_t stream) {
    const float* features = (const float*)d_in[0];   // [100000,128] f32
    const float* lw       = (const float*)d_in[1];   // [8,128,128]  f32
    const int*   nodes    = (const int*)d_in[2];     // [1024,8]     i32
    const int*   n1       = (const int*)d_in[3];     // [100000,10]  i32
    const int*   n2       = (const int*)d_in[4];     // [100000,10]  i32
    float*       out      = (float*)d_out;           // [1024,8,8,384] f32

    unsigned short* F  = (unsigned short*)d_ws;              // 3*8192*128 bf16
    unsigned short* Wp = F + (size_t)3 * N_NODES * FEAT;     // 1024*128 bf16

    pack_w<<<128, 256, 0, stream>>>(lw, Wp);
    gather_agg<<<N_NODES, 128, 0, stream>>>(features, nodes, n1, n2,
                                            F, F + (size_t)N_NODES * FEAT,
                                            F + (size_t)2 * N_NODES * FEAT);
    dim3 grid(24576 / 256, 1024 / 64);   // 96 x 16
    proj_mfma<<<grid, 256, 0, stream>>>(F, Wp, out);
}

// Round 4
// 92.243 us; speedup vs baseline: 1.9084x; 1.1196x over previous
//
#include <hip/hip_runtime.h>

typedef __attribute__((ext_vector_type(8))) short bf16x8;
typedef __attribute__((ext_vector_type(4))) float f32x4;

static constexpr int N_NODES = 8192;   // B*L
static constexpr int FEAT    = 128;
static constexpr int CS1     = 10;
static constexpr int CS2     = 10;
static constexpr int NROWS   = 111;    // 10 a1-rows + 100 a2-rows + 1 self
static constexpr int FEAT_BLOCKS = 6250;  // 100000*128/8 floats / 256 threads

__device__ __forceinline__ unsigned short f2bf(float f) {
    unsigned u = __builtin_bit_cast(unsigned, f);
    u += 0x7FFFu + ((u >> 16) & 1u);   // round-to-nearest-even
    return (unsigned short)(u >> 16);
}
__device__ __forceinline__ float bf2f(unsigned short h) {
    return __builtin_bit_cast(float, ((unsigned)h) << 16);
}

// ---------------- Kernel 0: pack features + W fp32 -> bf16 ----------------
__global__ void __launch_bounds__(256) pack_all(
    const float* __restrict__ feat, const float* __restrict__ lw,
    unsigned short* __restrict__ T, unsigned short* __restrict__ Wp)
{
    const int b = blockIdx.x;
    if (b < FEAT_BLOCKS) {
        // features: 12.8M floats, 8 per thread
        const size_t i = (size_t)b * 256 + threadIdx.x;
        const float4* src = (const float4*)feat;
        const float4 v0 = src[i * 2], v1 = src[i * 2 + 1];
        ushort4 o0, o1;
        o0.x = f2bf(v0.x); o0.y = f2bf(v0.y); o0.z = f2bf(v0.z); o0.w = f2bf(v0.w);
        o1.x = f2bf(v1.x); o1.y = f2bf(v1.y); o1.z = f2bf(v1.z); o1.w = f2bf(v1.w);
        ((ushort4*)T)[i * 2]     = o0;
        ((ushort4*)T)[i * 2 + 1] = o1;
    } else {
        // W: 131072 floats, 4 per thread
        const int i = (b - FEAT_BLOCKS) * 256 + threadIdx.x;
        const float4 v = ((const float4*)lw)[i];
        ushort4 o;
        o.x = f2bf(v.x); o.y = f2bf(v.y); o.z = f2bf(v.z); o.w = f2bf(v.w);
        ((ushort4*)Wp)[i] = o;
    }
}

// ---------------- Kernel 1: gather + aggregate (bf16 table) ----------------
// One node per block, 128 threads = 4 groups of 32 lanes; each group reads one
// 256B bf16 row per iteration (ushort4/lane). Indices staged in LDS first.
__global__ void __launch_bounds__(128) gather_agg(
    const unsigned short* __restrict__ T,
    const int*   __restrict__ nodes,
    const int*   __restrict__ n1,
    const int*   __restrict__ n2,
    unsigned short* __restrict__ F0,
    unsigned short* __restrict__ F1,
    unsigned short* __restrict__ F2)
{
    __shared__ int   idx[NROWS];        // [0..9]=1-hop, [10..109]=2-hop, [110]=self
    __shared__ int   sm_m[CS2];
    __shared__ float redA[4][FEAT];
    __shared__ float redB[4][FEAT];

    const int n   = blockIdx.x;
    const int tid = threadIdx.x;
    const int nf  = nodes[n];

    // ---- index phase (parallel, 2-level) ----
    if (tid < CS1)                 idx[tid]        = n1[nf * CS1 + tid];
    else if (tid < CS1 + CS2)      sm_m[tid - CS1] = n2[nf * CS2 + (tid - CS1)];
    if (tid == 120)                idx[110]        = nf;
    __syncthreads();
    if (tid < CS1 * CS2) {
        const int t = tid / 10, s = tid - t * 10;
        idx[10 + tid] = n1[sm_m[t] * CS1 + s];
    }
    __syncthreads();

    // ---- gather phase ----
    const int g = tid >> 5;   // group 0..3
    const int l = tid & 31;   // lane in group; covers dims l*4..l*4+3
    f32x4 accA = {0.f, 0.f, 0.f, 0.f};
    f32x4 accB = {0.f, 0.f, 0.f, 0.f};

#pragma unroll
    for (int r = g; r < NROWS; r += 4) {
        const int row = idx[r];
        const ushort4 v = *(const ushort4*)(T + (size_t)row * FEAT + l * 4);
        if (r == 110) {
            *(ushort4*)(F2 + (size_t)n * FEAT + l * 4) = v;   // self row, already bf16
        } else {
            f32x4 f = {bf2f(v.x), bf2f(v.y), bf2f(v.z), bf2f(v.w)};
            if (r < 10) accA += f; else accB += f;
        }
    }

    *(f32x4*)&redA[g][l * 4] = accA;
    *(f32x4*)&redB[g][l * 4] = accB;
    __syncthreads();

    // ---- cross-group reduce + bf16 write ----
    if (tid < 32) {
        f32x4 s = {0.f, 0.f, 0.f, 0.f};
#pragma unroll
        for (int gg = 0; gg < 4; ++gg) s += *(const f32x4*)&redA[gg][tid * 4];
        s *= 0.1f;
        ushort4 o; o.x = f2bf(s.x); o.y = f2bf(s.y); o.z = f2bf(s.z); o.w = f2bf(s.w);
        *(ushort4*)(F0 + (size_t)n * FEAT + tid * 4) = o;
    } else if (tid < 64) {
        const int l2 = tid - 32;
        f32x4 s = {0.f, 0.f, 0.f, 0.f};
#pragma unroll
        for (int gg = 0; gg < 4; ++gg) s += *(const f32x4*)&redB[gg][l2 * 4];
        s *= 0.01f;
        ushort4 o; o.x = f2bf(s.x); o.y = f2bf(s.y); o.z = f2bf(s.z); o.w = f2bf(s.w);
        *(ushort4*)(F1 + (size_t)n * FEAT + l2 * 4) = o;
    }
}

// ---------------- Kernel 2: bf16 MFMA GEMM + ReLU ----------------
// C[x][y] = relu(sum_d X[x][d] * W[y][d]),  X=[24576][128] bf16 (x = j*8192+n),
// W=[1024][128] bf16 (y = c*128+k).  out flat: n*3072 + c*384 + j*128 + k
__global__ void __launch_bounds__(256) proj_mfma(
    const unsigned short* __restrict__ F,
    const unsigned short* __restrict__ Wp,
    float* __restrict__ out)
{
    const int wave = threadIdx.x >> 6;
    const int lane = threadIdx.x & 63;
    const int xBase = blockIdx.x * 256 + wave * 64;
    const int yBase = blockIdx.y * 64;
    const int r = lane & 15;   // A row / B col within 16-tile
    const int q = lane >> 4;   // k-slot (8 contiguous K elems each)

    f32x4 acc[4][4];
#pragma unroll
    for (int mi = 0; mi < 4; ++mi)
#pragma unroll
        for (int nj = 0; nj < 4; ++nj) acc[mi][nj] = (f32x4){0.f, 0.f, 0.f, 0.f};

    const unsigned short* Arow = F  + (size_t)(xBase + r) * FEAT + q * 8;
    const unsigned short* Brow = Wp + (size_t)(yBase + r) * FEAT + q * 8;

#pragma unroll
    for (int k0 = 0; k0 < 4; ++k0) {           // K step = 32
        bf16x8 a[4], b[4];
#pragma unroll
        for (int mi = 0; mi < 4; ++mi)
            a[mi] = *(const bf16x8*)(Arow + (size_t)mi * 16 * FEAT + k0 * 32);
#pragma unroll
        for (int nj = 0; nj < 4; ++nj)
            b[nj] = *(const bf16x8*)(Brow + (size_t)nj * 16 * FEAT + k0 * 32);
#pragma unroll
        for (int mi = 0; mi < 4; ++mi)
#pragma unroll
            for (int nj = 0; nj < 4; ++nj)
                acc[mi][nj] = __builtin_amdgcn_mfma_f32_16x16x32_bf16(
                    a[mi], b[nj], acc[mi][nj], 0, 0, 0);
    }

    // epilogue: C/D layout col=lane&15, row=(lane>>4)*4+reg (m89-verified)
#pragma unroll
    for (int mi = 0; mi < 4; ++mi) {
#pragma unroll
        for (int i = 0; i < 4; ++i) {
            const int x = xBase + mi * 16 + q * 4 + i;
            const int n = x & 8191;
            const int j = x >> 13;
            float* orow = out + (size_t)n * 3072 + j * 128;
#pragma unroll
            for (int nj = 0; nj < 4; ++nj) {
                const int y = yBase + nj * 16 + r;
                const int c = y >> 7;
                const int k = y & 127;
                orow[c * 384 + k] = fmaxf(acc[mi][nj][i], 0.f);
            }
        }
    }
}

extern "C" void kernel_launch(void* const* d_in, const int* in_sizes, int n_in,
                              void* d_out, int out_size, void* d_ws, size_t ws_size,
                              hipStream_t stream) {
    const float* features = (const float*)d_in[0];   // [100000,128] f32
    const float* lw       = (const float*)d_in[1];   // [8,128,128]  f32
    const int*   nodes    = (const int*)d_in[2];     // [1024,8]     i32
    const int*   n1       = (const int*)d_in[3];     // [100000,10]  i32
    const int*   n2       = (const int*)d_in[4];     // [100000,10]  i32
    float*       out      = (float*)d_out;           // [1024,8,8,384] f32

    unsigned short* F  = (unsigned short*)d_ws;              // 3*8192*128 bf16 = 6.3 MB
    unsigned short* Wp = F  + (size_t)3 * N_NODES * FEAT;    // 1024*128 bf16 = 256 KB
    unsigned short* T  = Wp + (size_t)1024 * FEAT;           // 100000*128 bf16 = 25.6 MB

    pack_all<<<FEAT_BLOCKS + 128, 256, 0, stream>>>(features, lw, T, Wp);
    gather_agg<<<N_NODES, 128, 0, stream>>>(T, nodes, n1, n2,
                                            F, F + (size_t)N_NODES * FEAT,
                                            F + (size_t)2 * N_NODES * FEAT);
    dim3 grid(24576 / 256, 1024 / 64);   // 96 x 16
    proj_mfma<<<grid, 256, 0, stream>>>(F, Wp, out);
}

// Round 8
// 81.727 us; speedup vs baseline: 2.1540x; 1.1287x over previous
//
#include <hip/hip_runtime.h>

typedef __attribute__((ext_vector_type(8))) short bf16x8;
typedef __attribute__((ext_vector_type(4))) float f32x4;

static constexpr int N_NODES = 8192;   // B*L
static constexpr int FEAT    = 128;
static constexpr int CS1     = 10;
static constexpr int CS2     = 10;
static constexpr int FEAT_BLOCKS = 6250;  // 100000*128/8 floats / 256 threads

__device__ __forceinline__ unsigned short f2bf(float f) {
    unsigned u = __builtin_bit_cast(unsigned, f);
    u += 0x7FFFu + ((u >> 16) & 1u);   // round-to-nearest-even
    return (unsigned short)(u >> 16);
}
__device__ __forceinline__ float bf2f(unsigned short h) {
    return __builtin_bit_cast(float, ((unsigned)h) << 16);
}
__device__ __forceinline__ void acc8(float* a, const uint4 v) {
    a[0] += bf2f((unsigned short)(v.x & 0xffffu));
    a[1] += bf2f((unsigned short)(v.x >> 16));
    a[2] += bf2f((unsigned short)(v.y & 0xffffu));
    a[3] += bf2f((unsigned short)(v.y >> 16));
    a[4] += bf2f((unsigned short)(v.z & 0xffffu));
    a[5] += bf2f((unsigned short)(v.z >> 16));
    a[6] += bf2f((unsigned short)(v.w & 0xffffu));
    a[7] += bf2f((unsigned short)(v.w >> 16));
}

// ---------------- Kernel 0: pack features + W fp32 -> bf16 ----------------
__global__ void __launch_bounds__(256) pack_all(
    const float* __restrict__ feat, const float* __restrict__ lw,
    unsigned short* __restrict__ T, unsigned short* __restrict__ Wp)
{
    const int b = blockIdx.x;
    if (b < FEAT_BLOCKS) {
        const size_t i = (size_t)b * 256 + threadIdx.x;
        const f32x4* src = (const f32x4*)feat;
        const f32x4 v0 = __builtin_nontemporal_load(src + i * 2);
        const f32x4 v1 = __builtin_nontemporal_load(src + i * 2 + 1);
        ushort4 o0, o1;
        o0.x = f2bf(v0[0]); o0.y = f2bf(v0[1]); o0.z = f2bf(v0[2]); o0.w = f2bf(v0[3]);
        o1.x = f2bf(v1[0]); o1.y = f2bf(v1[1]); o1.z = f2bf(v1[2]); o1.w = f2bf(v1[3]);
        ((ushort4*)T)[i * 2]     = o0;
        ((ushort4*)T)[i * 2 + 1] = o1;
    } else {
        const int i = (b - FEAT_BLOCKS) * 256 + threadIdx.x;
        const float4 v = ((const float4*)lw)[i];
        ushort4 o;
        o.x = f2bf(v.x); o.y = f2bf(v.y); o.z = f2bf(v.z); o.w = f2bf(v.w);
        ((ushort4*)Wp)[i] = o;
    }
}

// ---------------- Kernel 1: gather + aggregate (bf16 table) ----------------
// 128 threads = 8 groups x 16 lanes; lane covers 8 dims (16B dwordx4).
// 14 unconditional row loads per thread (idx padded to 112), max MLP.
__global__ void __launch_bounds__(128) gather_agg(
    const unsigned short* __restrict__ T,
    const int*   __restrict__ nodes,
    const int*   __restrict__ n1,
    const int*   __restrict__ n2,
    unsigned short* __restrict__ F0,
    unsigned short* __restrict__ F1,
    unsigned short* __restrict__ F2)
{
    __shared__ int   idx[112];   // [0..9]=1-hop, [10..109]=2-hop, [110]=self, [111]=dummy
    __shared__ int   sm_m[CS2];
    __shared__ float red[8][2][FEAT];   // [group][A/B][dim]

    const int n   = blockIdx.x;
    const int tid = threadIdx.x;
    const int nf  = nodes[n];

    // ---- index phase ----
    if (tid < CS1)                 idx[tid]        = n1[nf * CS1 + tid];
    else if (tid < CS1 + CS2)      sm_m[tid - CS1] = n2[nf * CS2 + (tid - CS1)];
    else if (tid == 20)          { idx[110] = nf; idx[111] = 0; }
    __syncthreads();
    if (tid < CS1 * CS2) {
        const int t = tid / 10, s = tid - t * 10;
        idx[10 + tid] = n1[sm_m[t] * CS1 + s];
    }
    __syncthreads();

    // ---- gather phase ----
    const int g = tid >> 4;    // group 0..7, handles rows g, g+8, ..., g+104
    const int l = tid & 15;    // dims l*8 .. l*8+7
    const unsigned short* Tl = T + l * 8;

    uint4 v[14];
#pragma unroll
    for (int t = 0; t < 14; ++t) {
        const int row = idx[g + t * 8];
        v[t] = *(const uint4*)(Tl + (size_t)row * FEAT);
    }

    float aA[8] = {0,0,0,0,0,0,0,0};
    float aB[8] = {0,0,0,0,0,0,0,0};
    acc8(aA, v[0]);                              // rows 0..7: 1-hop
    if (g < 2) acc8(aA, v[1]); else acc8(aB, v[1]);   // rows 8..15: 8,9 are 1-hop
#pragma unroll
    for (int t = 2; t < 13; ++t) acc8(aB, v[t]); // rows 16..103: 2-hop
    if (g < 6)      acc8(aB, v[13]);             // rows 104..109: 2-hop
    else if (g == 6)                             // row 110: self
        *(uint4*)(F2 + (size_t)n * FEAT + l * 8) = v[13];
    // g == 7, t == 13 -> dummy row, discarded

#pragma unroll
    for (int h = 0; h < 2; ++h) {
        *(f32x4*)&red[g][0][l * 8 + h * 4] = *(const f32x4*)&aA[h * 4];
        *(f32x4*)&red[g][1][l * 8 + h * 4] = *(const f32x4*)&aB[h * 4];
    }
    __syncthreads();

    // ---- cross-group reduce + bf16 write ----
    if (tid < 64) {
        const int sel = tid >> 5;          // 0 = feats1, 1 = feats2
        const int d4  = (tid & 31) * 4;
        f32x4 s = {0.f, 0.f, 0.f, 0.f};
#pragma unroll
        for (int gg = 0; gg < 8; ++gg) s += *(const f32x4*)&red[gg][sel][d4];
        s *= sel ? 0.01f : 0.1f;
        ushort4 o; o.x = f2bf(s.x); o.y = f2bf(s.y); o.z = f2bf(s.z); o.w = f2bf(s.w);
        unsigned short* dst = (sel ? F1 : F0) + (size_t)n * FEAT + d4;
        *(ushort4*)dst = o;
    }
}

// ---------------- Kernel 2: bf16 MFMA GEMM + ReLU ----------------
// C[x][y] = relu(sum_d X[x][d] * W[y][d]),  X=[24576][128] bf16 (x = j*8192+n),
// W=[1024][128] bf16 (y = c*128+k).  out flat: n*3072 + c*384 + j*128 + k
__global__ void __launch_bounds__(256) proj_mfma(
    const unsigned short* __restrict__ F,
    const unsigned short* __restrict__ Wp,
    float* __restrict__ out)
{
    __shared__ float st[4][16][65];   // wave-private transpose stage, 16.6 KB

    const int wave = threadIdx.x >> 6;
    const int lane = threadIdx.x & 63;
    const int xBase = blockIdx.x * 256 + wave * 64;
    const int yBase = blockIdx.y * 64;
    const int r = lane & 15;   // A row / B col within 16-tile
    const int q = lane >> 4;   // k-slot (8 contiguous K elems each)

    f32x4 acc[4][4];
#pragma unroll
    for (int mi = 0; mi < 4; ++mi)
#pragma unroll
        for (int nj = 0; nj < 4; ++nj) acc[mi][nj] = (f32x4){0.f, 0.f, 0.f, 0.f};

    const unsigned short* Arow = F  + (size_t)(xBase + r) * FEAT + q * 8;
    const unsigned short* Brow = Wp + (size_t)(yBase + r) * FEAT + q * 8;

#pragma unroll
    for (int k0 = 0; k0 < 4; ++k0) {           // K step = 32
        bf16x8 a[4], b[4];
#pragma unroll
        for (int mi = 0; mi < 4; ++mi)
            a[mi] = *(const bf16x8*)(Arow + (size_t)mi * 16 * FEAT + k0 * 32);
#pragma unroll
        for (int nj = 0; nj < 4; ++nj)
            b[nj] = *(const bf16x8*)(Brow + (size_t)nj * 16 * FEAT + k0 * 32);
#pragma unroll
        for (int mi = 0; mi < 4; ++mi)
#pragma unroll
            for (int nj = 0; nj < 4; ++nj)
                acc[mi][nj] = __builtin_amdgcn_mfma_f32_16x16x32_bf16(
                    a[mi], b[nj], acc[mi][nj], 0, 0, 0);
    }

    // epilogue: per-wave LDS transpose so each lane stores a contiguous float4.
    // C/D layout: col = lane&15 (r), row = q*4 + reg (m89-verified).
    const int c = yBase >> 7;
    const int kBase = (yBase & 127) + r * 4;
#pragma unroll
    for (int mi = 0; mi < 4; ++mi) {
#pragma unroll
        for (int i = 0; i < 4; ++i)
#pragma unroll
            for (int nj = 0; nj < 4; ++nj)
                st[wave][q * 4 + i][nj * 16 + r] = acc[mi][nj][i];
        // wave-private region: no barrier needed, compiler orders via lgkmcnt
#pragma unroll
        for (int rr = 0; rr < 4; ++rr) {
            const int row = rr * 4 + q;
            const f32x4 vv = *(const f32x4*)&st[wave][row][r * 4];
            const int x = xBase + mi * 16 + row;
            const int n = x & 8191;
            const int j = x >> 13;
            f32x4 o;
            o[0] = fmaxf(vv[0], 0.f); o[1] = fmaxf(vv[1], 0.f);
            o[2] = fmaxf(vv[2], 0.f); o[3] = fmaxf(vv[3], 0.f);
            __builtin_nontemporal_store(o,
                (f32x4*)(out + (size_t)n * 3072 + c * 384 + j * 128 + kBase));
        }
    }
}

extern "C" void kernel_launch(void* const* d_in, const int* in_sizes, int n_in,
                              void* d_out, int out_size, void* d_ws, size_t ws_size,
                              hipStream_t stream) {
    const float* features = (const float*)d_in[0];   // [100000,128] f32
    const float* lw       = (const float*)d_in[1];   // [8,128,128]  f32
    const int*   nodes    = (const int*)d_in[2];     // [1024,8]     i32
    const int*   n1       = (const int*)d_in[3];     // [100000,10]  i32
    const int*   n2       = (const int*)d_in[4];     // [100000,10]  i32
    float*       out      = (float*)d_out;           // [1024,8,8,384] f32

    unsigned short* F  = (unsigned short*)d_ws;              // 3*8192*128 bf16 = 6.3 MB
    unsigned short* Wp = F  + (size_t)3 * N_NODES * FEAT;    // 1024*128 bf16 = 256 KB
    unsigned short* T  = Wp + (size_t)1024 * FEAT;           // 100000*128 bf16 = 25.6 MB

    pack_all<<<FEAT_BLOCKS + 128, 256, 0, stream>>>(features, lw, T, Wp);
    gather_agg<<<N_NODES, 128, 0, stream>>>(T, nodes, n1, n2,
                                            F, F + (size_t)N_NODES * FEAT,
                                            F + (size_t)2 * N_NODES * FEAT);
    dim3 grid(24576 / 256, 1024 / 64);   // 96 x 16
    proj_mfma<<<grid, 256, 0, stream>>>(F, Wp, out);
}